// Round 6
// baseline (241.699 us; speedup 1.0000x reference)
//
#include <hip/hip_runtime.h>
#include <math.h>

#define Bn 64
#define Tn 2048
#define NCLS 20
#define Dn 2048
#define LCSL 64
#define FSDL 32

typedef __bf16 bf16x4 __attribute__((ext_vector_type(4)));
typedef __bf16 bf16x8 __attribute__((ext_vector_type(8)));
typedef float f32x4 __attribute__((ext_vector_type(4)));

// ws float offsets (no atomics; every consumed slot written each call)
#define WS_LCS 0         // 64   lcs dp results
#define WS_FSD 64        // 64   fsd dp results
#define WS_NORM 128      // 384  feat norms
#define WS_GS 512        // 512  guide/sparse partials [128 blocks][4]
#define WS_LSQ 1024      // 512*128 lcs sumsq partials [(b*8+ks)*128 + e]
#define WS_FSQ 66560     // 512*64  fsd sumsq partials [((b*2+half)*4+ks)*64 + e]
#define WS_SPART 99328   // 64*8*4096 lcs S partials [(b*8+ks)*4096]
#define WS_MG 2196480    // 64*2*4*1024 fsd partials [((b*2+half)*4+ks)*1024]

// ============ mega kernel ============
// blocks 0..511     : LCS partial GEMM via MFMA (b=bid>>3, ks=bid&7, K=256 single-stage)
// blocks 512..1023  : FSD partial GEMM via MFMA (b, half, ks; K=256 single-stage)
// blocks 1024..1151 : guide+sparse partial reductions
// blocks 1152..1247 : feature norms (384 rows, wave per row)
__global__ __launch_bounds__(256) void mega_kernel(
    const float* __restrict__ lcs0, const float* __restrict__ lcs1,
    const float* __restrict__ fA0, const float* __restrict__ fA1,
    const float* __restrict__ fB1,
    const float* __restrict__ vid0, const float* __restrict__ vid1,
    const float* __restrict__ cas0, const float* __restrict__ att0,
    const float* __restrict__ cas1, const float* __restrict__ att1,
    const float* __restrict__ f0, const float* __restrict__ f1,
    const float* __restrict__ f2, const float* __restrict__ f3,
    const float* __restrict__ f4, const float* __restrict__ f5,
    float* __restrict__ ws) {
    // bf16 [row][k=256], row stride 256 elems (512 B); 8-elem chunk XOR-swizzled by row&7
    __shared__ __align__(16) __bf16 tA[64 * 256];   // 32 KB
    __shared__ __align__(16) __bf16 tB[64 * 256];   // 32 KB
    const int t = threadIdx.x;
    const int bid = blockIdx.x;
    const int w = t >> 6, lane = t & 63;
    const int quad = lane >> 4, l16 = lane & 15;

    if (bid < 512) {
        // -------- LCS partial GEMM: out 64x64, K=256, single LDS stage --------
        const int b = bid >> 3, ks = bid & 7;
        const float* c0 = lcs0 + (size_t)b * LCSL * Dn + ks * 256;
        const float* c1 = lcs1 + (size_t)b * LCSL * Dn + ks * 256;

        // each wave owns rows w*16 .. w*16+15; one load instruction = one full
        // 1-KB contiguous row-slice (64 lanes x 16 B)
        float4 pA[16], pB[16];
        #pragma unroll
        for (int r = 0; r < 16; ++r)
            pA[r] = *(const float4*)(c0 + (size_t)(w * 16 + r) * Dn + lane * 4);
        #pragma unroll
        for (int r = 0; r < 16; ++r)
            pB[r] = *(const float4*)(c1 + (size_t)(w * 16 + r) * Dn + lane * 4);

        float* qsq = ws + WS_LSQ + (size_t)(b * 8 + ks) * 128;
        #pragma unroll
        for (int r = 0; r < 16; ++r) {
            int rr = w * 16 + r;
            float4 av = pA[r];
            bf16x4 a4 = {(__bf16)av.x, (__bf16)av.y, (__bf16)av.z, (__bf16)av.w};
            int c = (lane >> 1) ^ (rr & 7);
            *(bf16x4*)&tA[rr * 256 + (c << 3) + ((lane & 1) << 2)] = a4;
            float sa = av.x * av.x + av.y * av.y + av.z * av.z + av.w * av.w;
            #pragma unroll
            for (int m = 1; m < 64; m <<= 1) sa += __shfl_xor(sa, m);
            if (lane == 0) qsq[rr] = sa;
        }
        #pragma unroll
        for (int r = 0; r < 16; ++r) {
            int rr = w * 16 + r;
            float4 bv = pB[r];
            bf16x4 b4 = {(__bf16)bv.x, (__bf16)bv.y, (__bf16)bv.z, (__bf16)bv.w};
            int c = (lane >> 1) ^ (rr & 7);
            *(bf16x4*)&tB[rr * 256 + (c << 3) + ((lane & 1) << 2)] = b4;
            float sb = bv.x * bv.x + bv.y * bv.y + bv.z * bv.z + bv.w * bv.w;
            #pragma unroll
            for (int m = 1; m < 64; m <<= 1) sb += __shfl_xor(sb, m);
            if (lane == 0) qsq[64 + rr] = sb;
        }
        __syncthreads();

        f32x4 acc[4] = {};
        const int ar = w * 16 + l16;
        #pragma unroll
        for (int s = 0; s < 8; ++s) {
            bf16x8 af = *(const bf16x8*)&tA[ar * 256 + ((((s * 4 + quad) ^ (ar & 7))) << 3)];
            #pragma unroll
            for (int tj = 0; tj < 4; ++tj) {
                int br = tj * 16 + l16;
                bf16x8 bf = *(const bf16x8*)&tB[br * 256 + ((((s * 4 + quad) ^ (br & 7))) << 3)];
                acc[tj] = __builtin_amdgcn_mfma_f32_16x16x32_bf16(af, bf, acc[tj], 0, 0, 0);
            }
        }
        float* dst = ws + WS_SPART + (size_t)(b * 8 + ks) * 4096;
        #pragma unroll
        for (int tj = 0; tj < 4; ++tj)
            #pragma unroll
            for (int rg = 0; rg < 4; ++rg)
                dst[(w * 16 + quad * 4 + rg) * 64 + tj * 16 + l16] = acc[tj][rg];
    } else if (bid < 1024) {
        // -------- FSD partial GEMM: out 32x32, K=256, single LDS stage --------
        const int qb = bid - 512;
        const int b = qb >> 3, half = (qb >> 2) & 1, ks = qb & 3;
        float ps = 0.f;
        for (int c = 0; c < NCLS; ++c) ps += vid0[b * NCLS + c] * vid1[b * NCLS + c];
        const float* base1 = (ps > 0.f) ? fA1 : fB1;
        const float* c0 = fA0 + (size_t)b * FSDL * Dn + half * 1024 + ks * 256;
        const float* c1 = base1 + (size_t)b * FSDL * Dn + half * 1024 + ks * 256;

        float4 pA[8], pB[8];
        #pragma unroll
        for (int r = 0; r < 8; ++r)
            pA[r] = *(const float4*)(c0 + (size_t)(w * 8 + r) * Dn + lane * 4);
        #pragma unroll
        for (int r = 0; r < 8; ++r)
            pB[r] = *(const float4*)(c1 + (size_t)(w * 8 + r) * Dn + lane * 4);

        float* qsq = ws + WS_FSQ + (size_t)((b * 2 + half) * 4 + ks) * 64;
        #pragma unroll
        for (int r = 0; r < 8; ++r) {
            int rr = w * 8 + r;
            float4 av = pA[r];
            bf16x4 a4 = {(__bf16)av.x, (__bf16)av.y, (__bf16)av.z, (__bf16)av.w};
            int c = (lane >> 1) ^ (rr & 7);
            *(bf16x4*)&tA[rr * 256 + (c << 3) + ((lane & 1) << 2)] = a4;
            float sa = av.x * av.x + av.y * av.y + av.z * av.z + av.w * av.w;
            #pragma unroll
            for (int m = 1; m < 64; m <<= 1) sa += __shfl_xor(sa, m);
            if (lane == 0) qsq[rr] = sa;
        }
        #pragma unroll
        for (int r = 0; r < 8; ++r) {
            int rr = w * 8 + r;
            float4 bv = pB[r];
            bf16x4 b4 = {(__bf16)bv.x, (__bf16)bv.y, (__bf16)bv.z, (__bf16)bv.w};
            int c = (lane >> 1) ^ (rr & 7);
            *(bf16x4*)&tB[rr * 256 + (c << 3) + ((lane & 1) << 2)] = b4;
            float sb = bv.x * bv.x + bv.y * bv.y + bv.z * bv.z + bv.w * bv.w;
            #pragma unroll
            for (int m = 1; m < 64; m <<= 1) sb += __shfl_xor(sb, m);
            if (lane == 0) qsq[32 + rr] = sb;
        }
        __syncthreads();

        const int wi = w >> 1, wj = w & 1;
        const int ar = wi * 16 + l16, br = wj * 16 + l16;
        f32x4 acc = {};
        #pragma unroll
        for (int s = 0; s < 8; ++s) {
            bf16x8 af = *(const bf16x8*)&tA[ar * 256 + ((((s * 4 + quad) ^ (ar & 7))) << 3)];
            bf16x8 bf = *(const bf16x8*)&tB[br * 256 + ((((s * 4 + quad) ^ (br & 7))) << 3)];
            acc = __builtin_amdgcn_mfma_f32_16x16x32_bf16(af, bf, acc, 0, 0, 0);
        }
        float* dst = ws + WS_MG + (size_t)((b * 2 + half) * 4 + ks) * 1024;
        #pragma unroll
        for (int rg = 0; rg < 4; ++rg)
            dst[(wi * 16 + quad * 4 + rg) * 32 + wj * 16 + l16] = acc[rg];
    } else if (bid < 1152) {
        // -------- guide + sparse partials --------
        const int gb = bid - 1024;
        const int N = Bn * Tn;
        float g0 = 0.f, s0 = 0.f, g1 = 0.f, s1 = 0.f;
        for (int n = gb * 256 + t; n < 2 * N; n += 128 * 256) {
            int sfx = (n >= N);
            int m = sfx ? (n - N) : n;
            const float* cas = sfx ? cas1 : cas0;
            const float* att = sfx ? att1 : att0;
            float a0 = att[m * 3 + 0];
            float a1 = att[m * 3 + 1];
            float g = fabsf(1.0f - cas[m * (NCLS + 1) + NCLS] - a0);
            float s = a0 + a1;
            if (sfx) { g1 += g; s1 += s; } else { g0 += g; s0 += s; }
        }
        float* red = (float*)tA;  // 4 KB scratch
        float vals[4] = {g0, s0, g1, s1};
        #pragma unroll
        for (int v = 0; v < 4; ++v) red[v * 256 + t] = vals[v];
        __syncthreads();
        for (int o = 128; o; o >>= 1) {
            if (t < o) {
                #pragma unroll
                for (int v = 0; v < 4; ++v) red[v * 256 + t] += red[v * 256 + t + o];
            }
            __syncthreads();
        }
        if (t < 4) ws[WS_GS + gb * 4 + t] = red[t * 256];
    } else {
        // -------- feature norms: 384 rows, wave per row --------
        int R = (bid - 1152) * 4 + w;
        const float* arr[6] = {f0, f1, f2, f3, f4, f5};
        const float* p = arr[R >> 6] + (size_t)(R & 63) * Dn;
        float s = 0.f;
        #pragma unroll
        for (int qd = 0; qd < 8; ++qd) {
            float4 v = *(const float4*)(p + qd * 256 + lane * 4);
            s += v.x * v.x + v.y * v.y + v.z * v.z + v.w * v.w;
        }
        for (int off = 32; off; off >>= 1) s += __shfl_down(s, off);
        if (lane == 0) ws[WS_NORM + R] = sqrtf(s);
    }
}

// ============ dp kernel: LCS (0..63) + FSD (64..127), 256 threads ============
__global__ __launch_bounds__(256) void dp_kernel(float* __restrict__ ws) {
    const int t = threadIdx.x;
    if (blockIdx.x < 64) {
        const int b = blockIdx.x;
        __shared__ float S[64 * 68];
        __shared__ float inv[128];
        if (t < 128) {
            float s = 0.f;
            #pragma unroll
            for (int ks = 0; ks < 8; ++ks)
                s += ws[WS_LSQ + (size_t)(b * 8 + ks) * 128 + t];
            inv[t] = 1.0f / sqrtf(s);
        }
        __syncthreads();
        const float* sp = ws + WS_SPART + (size_t)b * 32768;
        #pragma unroll
        for (int qd = 0; qd < 4; ++qd) {
            int idx4 = qd * 256 + t;
            int i = idx4 >> 4, j = (idx4 & 15) * 4;
            float4 v = {0.f, 0.f, 0.f, 0.f};
            #pragma unroll
            for (int ks = 0; ks < 8; ++ks) {
                float4 p = *(const float4*)(sp + (size_t)ks * 4096 + idx4 * 4);
                v.x += p.x; v.y += p.y; v.z += p.z; v.w += p.w;
            }
            float ri = inv[i];
            S[i * 68 + j + 0] = v.x * ri * inv[64 + j + 0];
            S[i * 68 + j + 1] = v.y * ri * inv[64 + j + 1];
            S[i * 68 + j + 2] = v.z * ri * inv[64 + j + 2];
            S[i * 68 + j + 3] = v.w * ri * inv[64 + j + 3];
        }
        __syncthreads();
        if (t < 64) {
            float prev = 0.f, prevprev = 0.f;
            float sval_next = S[t * 68 + 0];
            for (int d = 2; d <= 128; ++d) {
                float s = sval_next;
                int jn = d - t - 1;
                if (jn >= 0 && jn < 64) sval_next = S[t * 68 + jn];
                float up = __shfl_up(prev, 1);
                float dg = __shfl_up(prevprev, 1);
                if (t == 0) { up = 0.f; dg = 0.f; }
                int j = d - t - 1;
                float left = prev;
                float val = (s > 0.5f) ? (dg + s) : fmaxf(up, left);
                float cur = (j >= 1 && j <= 64) ? val : 0.f;
                prevprev = prev;
                prev = cur;
            }
            if (t == 63) ws[WS_LCS + b] = prev;
        }
    } else {
        const int b = blockIdx.x - 64;
        __shared__ float M[32 * 36], G[32 * 36];
        __shared__ float inv[128];
        if (t < 128) {
            int half = t >> 6, sub = t & 63;
            float s = 0.f;
            #pragma unroll
            for (int ks = 0; ks < 4; ++ks)
                s += ws[WS_FSQ + (size_t)((b * 2 + half) * 4 + ks) * 64 + sub];
            inv[t] = 1.0f / sqrtf(s);
        }
        __syncthreads();
        {
            int idx4 = t;
            int i = idx4 >> 3, j = (idx4 & 7) * 4;
            float4 vM = {0.f, 0.f, 0.f, 0.f}, vG = {0.f, 0.f, 0.f, 0.f};
            #pragma unroll
            for (int ks = 0; ks < 4; ++ks) {
                float4 pM = *(const float4*)(ws + WS_MG + (size_t)((b * 2 + 0) * 4 + ks) * 1024 + idx4 * 4);
                float4 pG = *(const float4*)(ws + WS_MG + (size_t)((b * 2 + 1) * 4 + ks) * 1024 + idx4 * 4);
                vM.x += pM.x; vM.y += pM.y; vM.z += pM.z; vM.w += pM.w;
                vG.x += pG.x; vG.y += pG.y; vG.z += pG.z; vG.w += pG.w;
            }
            float riM = inv[i], riG = inv[64 + i];
            M[i * 36 + j + 0] = vM.x * riM * inv[32 + j + 0];
            M[i * 36 + j + 1] = vM.y * riM * inv[32 + j + 1];
            M[i * 36 + j + 2] = vM.z * riM * inv[32 + j + 2];
            M[i * 36 + j + 3] = vM.w * riM * inv[32 + j + 3];
            G[i * 36 + j + 0] = vG.x * riG * inv[96 + j + 0];
            G[i * 36 + j + 1] = vG.y * riG * inv[96 + j + 1];
            G[i * 36 + j + 2] = vG.z * riG * inv[96 + j + 2];
            G[i * 36 + j + 3] = vG.w * riG * inv[96 + j + 3];
        }
        __syncthreads();
        if (t < 32) {
            float prev = 0.f, prevprev = 0.f;
            float m_next = M[t * 36 + 0], g_next = G[t * 36 + 0];
            for (int d = 2; d <= 64; ++d) {
                float m = m_next, g = g_next;
                int jn = d - t - 1;
                if (jn >= 0 && jn < 32) { m_next = M[t * 36 + jn]; g_next = G[t * 36 + jn]; }
                float up = __shfl_up(prev, 1);
                float dg = __shfl_up(prevprev, 1);
                if (t == 0) { up = 0.f; dg = 0.f; }
                int j = d - t - 1;
                float left = prev;
                float x0 = dg * 10.0f;
                float x1 = (g + up) * 10.0f;
                float x2 = (g + left) * 10.0f;
                float mx = fmaxf(x0, fmaxf(x1, x2));
                float lse = mx + __logf(__expf(x0 - mx) + __expf(x1 - mx) + __expf(x2 - mx));
                float val = m + 0.1f * lse;
                float cur = (j >= 1 && j <= 32) ? val : 0.f;
                prevprev = prev;
                prev = cur;
            }
            if (t == 31) ws[WS_FSD + b] = prev;
        }
    }
}

// ============ final combine ============
__device__ float block_reduce(float v, float* red, int t) {
    red[t] = v;
    __syncthreads();
    for (int o = 128; o; o >>= 1) {
        if (t < o) red[t] += red[t + o];
        __syncthreads();
    }
    float r = red[0];
    __syncthreads();
    return r;
}

__global__ __launch_bounds__(256) void final_kernel(
    const float* __restrict__ ai0, const float* __restrict__ ac0,
    const float* __restrict__ ab0, const float* __restrict__ vid0,
    const float* __restrict__ ai1, const float* __restrict__ ac1,
    const float* __restrict__ ab1, const float* __restrict__ vid1,
    const float* __restrict__ ws, float* __restrict__ out) {
    __shared__ float rs0[Bn], rs1[Bn], plsh[Bn];
    __shared__ float red[256];
    int t = threadIdx.x;
    if (t < Bn) {
        float s0 = 0.f, s1 = 0.f, pp = 0.f;
        for (int c = 0; c < NCLS; ++c) {
            float a = vid0[t * NCLS + c], bl = vid1[t * NCLS + c];
            s0 += a; s1 += bl; pp += a * bl;
        }
        rs0[t] = s0;
        rs1[t] = s1;
        plsh[t] = (pp > 0.f) ? 1.f : 0.f;
    }
    __syncthreads();

    float inst0 = 0.f, cont0 = 0.f, back0 = 0.f;
    float inst1 = 0.f, cont1 = 0.f, back1 = 0.f;
    for (int idx = t; idx < Bn * (NCLS + 1); idx += 256) {
        int b = idx / (NCLS + 1), c = idx % (NCLS + 1);
        float v0 = (c < NCLS) ? vid0[b * NCLS + c] : 0.f;
        float v1 = (c < NCLS) ? vid1[b * NCLS + c] : 0.f;
        float wI0 = (c < NCLS) ? (v0 / rs0[b]) : 0.f;
        float wC0 = ((c < NCLS) ? v0 : 1.f) / (rs0[b] + 1.f);
        float wI1 = (c < NCLS) ? (v1 / rs1[b]) : 0.f;
        float wC1 = ((c < NCLS) ? v1 : 1.f) / (rs1[b] + 1.f);
        inst0 += logf(ai0[idx] + 1e-10f) * wI0;
        cont0 += logf(ac0[idx] + 1e-10f) * wC0;
        inst1 += logf(ai1[idx] + 1e-10f) * wI1;
        cont1 += logf(ac1[idx] + 1e-10f) * wC1;
        if (c == NCLS) {
            back0 += logf(ab0[idx] + 1e-10f);
            back1 += logf(ab1[idx] + 1e-10f);
        }
    }
    float sInst0 = block_reduce(inst0, red, t);
    float sCont0 = block_reduce(cont0, red, t);
    float sBack0 = block_reduce(back0, red, t);
    float sInst1 = block_reduce(inst1, red, t);
    float sCont1 = block_reduce(cont1, red, t);
    float sBack1 = block_reduce(back1, red, t);

    float g0 = 0.f, s0v = 0.f, g1 = 0.f, s1v = 0.f;
    for (int i = t; i < 128; i += 256) {
        g0  += ws[WS_GS + i * 4 + 0];
        s0v += ws[WS_GS + i * 4 + 1];
        g1  += ws[WS_GS + i * 4 + 2];
        s1v += ws[WS_GS + i * 4 + 3];
    }
    float sG0 = block_reduce(g0, red, t);
    float sS0 = block_reduce(s0v, red, t);
    float sG1 = block_reduce(g1, red, t);
    float sS1 = block_reduce(s1v, red, t);

    float fv0 = 0.f, fv1 = 0.f;
    if (t < Bn) {
        const float* nm = ws + WS_NORM;
        {
            float ni = nm[0 * Bn + t], nc = nm[1 * Bn + t], nb = nm[2 * Bn + t];
            float f1 = fmaxf(50.0f - ni + nc, 0.f);
            float f2 = fmaxf(50.0f - nc + nb, 0.f);
            float f = f1 + f2 + nb;
            fv0 = f * f;
        }
        {
            float ni = nm[3 * Bn + t], nc = nm[4 * Bn + t], nb = nm[5 * Bn + t];
            float f1 = fmaxf(50.0f - ni + nc, 0.f);
            float f2 = fmaxf(50.0f - nc + nb, 0.f);
            float f = f1 + f2 + nb;
            fv1 = f * f;
        }
    }
    float sFeat0 = block_reduce(fv0, red, t) / (float)Bn;
    float sFeat1 = block_reduce(fv1, red, t) / (float)Bn;

    float posL = 0.f, negL = 0.f, posF = 0.f, negF = 0.f, pln = 0.f;
    if (t < Bn) {
        float pl = plsh[t];
        float lv = ws[WS_LCS + t];
        float fv = ws[WS_FSD + t];
        posL = lv * pl; negL = lv * (1.f - pl);
        posF = fv * pl; negF = fv * (1.f - pl);
        pln = pl;
    }
    float sPosL = block_reduce(posL, red, t);
    float sNegL = block_reduce(negL, red, t);
    float sPosF = block_reduce(posF, red, t);
    float sNegF = block_reduce(negF, red, t);
    float sPln = block_reduce(pln, red, t);

    if (t == 0) {
        float cls0 = -(sInst0 + sCont0 + sBack0) / (float)Bn;
        float cls1 = -(sInst1 + sCont1 + sBack1) / (float)Bn;
        float guide0 = sG0 / (float)Bn;
        float sparse0 = sS0 / (float)(Bn * 2);
        float guide1 = sG1 / (float)Bn;
        float sparse1 = sS1 / (float)(Bn * 2);
        float loss0 = cls0 + 1.0f * guide0 + 5e-05f * sFeat0 + 8e-05f * sparse0;
        float loss1 = cls1 + 1.0f * guide1 + 5e-05f * sFeat1 + 8e-05f * sparse1;
        float acm = 0.5f * (loss0 + loss1);
        float posn = sPln;
        float negn = (float)Bn - posn;
        float lcs_loss = sNegL / (negn + 1e-10f) - sPosL / (posn + 1e-10f);
        float fsd_loss = sNegF / (negn + 1e-10f) - sPosF / (posn + 1e-10f);
        out[0] = acm + 0.01f * lcs_loss + 0.01f * fsd_loss;
    }
}

extern "C" void kernel_launch(void* const* d_in, const int* in_sizes, int n_in,
                              void* d_out, int out_size, void* d_ws, size_t ws_size,
                              hipStream_t stream) {
    (void)in_sizes; (void)n_in; (void)out_size; (void)ws_size;
    const float* ai0  = (const float*)d_in[0];
    const float* ac0  = (const float*)d_in[1];
    const float* ab0  = (const float*)d_in[2];
    const float* vid0 = (const float*)d_in[3];
    const float* att0 = (const float*)d_in[4];
    const float* fi0  = (const float*)d_in[5];
    const float* fc0  = (const float*)d_in[6];
    const float* fb0  = (const float*)d_in[7];
    const float* cas0 = (const float*)d_in[8];
    const float* lcs0 = (const float*)d_in[9];
    const float* fsdA0 = (const float*)d_in[10];
    const float* ai1  = (const float*)d_in[12];
    const float* ac1  = (const float*)d_in[13];
    const float* ab1  = (const float*)d_in[14];
    const float* vid1 = (const float*)d_in[15];
    const float* att1 = (const float*)d_in[16];
    const float* fi1  = (const float*)d_in[17];
    const float* fc1  = (const float*)d_in[18];
    const float* fb1  = (const float*)d_in[19];
    const float* cas1 = (const float*)d_in[20];
    const float* lcs1 = (const float*)d_in[21];
    const float* fsdA1 = (const float*)d_in[22];
    const float* fsdB1 = (const float*)d_in[23];

    float* ws = (float*)d_ws;

    mega_kernel<<<1248, 256, 0, stream>>>(lcs0, lcs1, fsdA0, fsdA1, fsdB1,
                                          vid0, vid1, cas0, att0, cas1, att1,
                                          fi0, fc0, fb0, fi1, fc1, fb1, ws);
    dp_kernel<<<128, 256, 0, stream>>>(ws);
    final_kernel<<<1, 256, 0, stream>>>(ai0, ac0, ab0, vid0, ai1, ac1, ab1, vid1, ws,
                                        (float*)d_out);
}